// Round 4
// baseline (190.465 us; speedup 1.0000x reference)
//
#include <hip/hip_runtime.h>

#define NHID   512
#define NCLS   250
#define CHUNK  200
#define NTOK   2048
#define NOUT   450
#define NPANW  13              // ceil(CHUNK/16) word panels per class
#define NBLK   250             // one block per class
#define NTHR   512             // 8 waves: 8 independent DMA streams per CU
#define MAXTOK 64

typedef __attribute__((ext_vector_type(8))) short bf16x8;
typedef __attribute__((ext_vector_type(4))) float f32x4;

#define MFMA(a, b, c) __builtin_amdgcn_mfma_f32_16x16x32_bf16((a), (b), (c), 0, 0, 0)

__device__ __forceinline__ unsigned hpack(unsigned a, unsigned b) {
    return __builtin_amdgcn_perm(a, b, 0x07060302u);
}

// fp32x8 -> hi/lo split bf16x8 (truncate hi; lo = truncate(exact residual))
__device__ __forceinline__ void cvt8(float4 va, float4 vb, bf16x8& h, bf16x8& l) {
    unsigned u0 = __float_as_uint(va.x), u1 = __float_as_uint(va.y);
    unsigned u2 = __float_as_uint(va.z), u3 = __float_as_uint(va.w);
    unsigned u4 = __float_as_uint(vb.x), u5 = __float_as_uint(vb.y);
    unsigned u6 = __float_as_uint(vb.z), u7 = __float_as_uint(vb.w);
    union { unsigned w[4]; bf16x8 v; } H, L;
    H.w[0] = hpack(u1, u0); H.w[1] = hpack(u3, u2);
    H.w[2] = hpack(u5, u4); H.w[3] = hpack(u7, u6);
    float r0 = va.x - __uint_as_float(u0 & 0xffff0000u);
    float r1 = va.y - __uint_as_float(u1 & 0xffff0000u);
    float r2 = va.z - __uint_as_float(u2 & 0xffff0000u);
    float r3 = va.w - __uint_as_float(u3 & 0xffff0000u);
    float r4 = vb.x - __uint_as_float(u4 & 0xffff0000u);
    float r5 = vb.y - __uint_as_float(u5 & 0xffff0000u);
    float r6 = vb.z - __uint_as_float(u6 & 0xffff0000u);
    float r7 = vb.w - __uint_as_float(u7 & 0xffff0000u);
    L.w[0] = hpack(__float_as_uint(r1), __float_as_uint(r0));
    L.w[1] = hpack(__float_as_uint(r3), __float_as_uint(r2));
    L.w[2] = hpack(__float_as_uint(r5), __float_as_uint(r4));
    L.w[3] = hpack(__float_as_uint(r7), __float_as_uint(r6));
    h = H.v; l = L.v;
}

// async 16B/lane global->LDS (wave-uniform LDS base; HW adds lane*16;
// global source address is per-lane -> source-side swizzle is legal)
__device__ __forceinline__ void async16(const float* g, float* lds_base) {
    __builtin_amdgcn_global_load_lds(
        (const __attribute__((address_space(1))) unsigned*)g,
        (__attribute__((address_space(3))) unsigned*)lds_base, 16, 0, 0);
}

// DMA one 8KB k-quarter of a 16-row panel: [16 rows][128 floats], XOR-swizzled
// source slots (involution; reader applies the same XOR on its slot index)
__device__ __forceinline__ void issue_quarter(const float* wbase, int P, int kq,
                                              float* dst, int lane) {
    #pragma unroll
    for (int i = 0; i < 8; ++i) {
        int j  = 2 * i + (lane >> 5);               // row within panel
        int rj = P * 16 + j; if (rj > CHUNK - 1) rj = CHUNK - 1;
        int sl = (lane & 31) ^ (j & 7);             // 16B slot within quarter-row
        async16(wbase + (size_t)rj * NHID + kq * 128 + sl * 4, dst + i * 256);
    }
}

// one column (of 8) of an old p_class unit, 2-deep register pipeline
__device__ __forceinline__ void class_unit(int u, int wid, int lane, int n, int q,
                                           const float* __restrict__ x,
                                           const float* __restrict__ Wc,
                                           const float* __restrict__ bc,
                                           float* __restrict__ out) {
    const int mt = u >> 1, hn = u & 1;
    const int g4 = (wid >> 2) & 1, kk = wid & 3;
    const int rC = (hn * 8 + g4 * 4 + kk) * 16 + n;
    const bool rv = rC < NCLS;
    const int  rc = rv ? rC : NCLS - 1;
    const float* ap = x  + (size_t)(mt * 16 + n) * NHID + q * 8;
    const float* bp = Wc + (size_t)rc * NHID + q * 8;
    const float bias = bc[rc];
    f32x4 acc = {0.f, 0.f, 0.f, 0.f};
    float4 qa[2][2], qb[2][2];
    #pragma unroll
    for (int j = 0; j < 2; ++j) {
        qa[j][0] = *(const float4*)(ap + j * 32);
        qa[j][1] = *(const float4*)(ap + j * 32 + 4);
        qb[j][0] = *(const float4*)(bp + j * 32);
        qb[j][1] = *(const float4*)(bp + j * 32 + 4);
    }
    #pragma unroll 2
    for (int s = 0; s < 16; ++s) {
        const int b = s & 1;
        bf16x8 ah, al, bh, bl;
        cvt8(qa[b][0], qa[b][1], ah, al);
        cvt8(qb[b][0], qb[b][1], bh, bl);
        acc = MFMA(ah, bh, acc);
        acc = MFMA(al, bh, acc);
        acc = MFMA(ah, bl, acc);
        if (s + 2 < 16) {
            qa[b][0] = *(const float4*)(ap + (s + 2) * 32);
            qa[b][1] = *(const float4*)(ap + (s + 2) * 32 + 4);
            qb[b][0] = *(const float4*)(bp + (s + 2) * 32);
            qb[b][1] = *(const float4*)(bp + (s + 2) * 32 + 4);
        }
    }
    if (rv) {
        #pragma unroll
        for (int i = 0; i < 4; ++i)
            out[(size_t)(mt * 16 + q * 4 + i) * NOUT + rc] = acc[i] + bias;
    }
}

__global__ __launch_bounds__(NTHR)
void cbd_fused(const float* __restrict__ x,  const float* __restrict__ Wc,
               const float* __restrict__ bc, const float* __restrict__ Ww,
               const float* __restrict__ bw, const int* __restrict__ cls_idx,
               float* __restrict__ out)
{
    __shared__ float ringA[5][2][2048];   // waves 0-4: double 8KB quarter ring (80KB)
    __shared__ float ringB[3][2048];      // waves 5-7: single 8KB ring (24KB)
    __shared__ short Afrag[16384];        // 16 tok x 16 ks x 4 q x (ah|al) = 32KB
    __shared__ int   toktmp[MAXTOK];

    const int tid  = threadIdx.x;
    const int wid  = tid >> 6;
    const int lane = tid & 63;
    const int n    = lane & 15;
    const int q    = lane >> 4;
    const int c    = blockIdx.x;          // class

    // ---- per-wave redundant token scan (identical data per wave; benign) ----
    int myvals[32];
    #pragma unroll
    for (int it = 0; it < 8; ++it) {
        int4 v = *(const int4*)&cls_idx[it * 256 + lane * 4];
        myvals[it*4+0] = v.x; myvals[it*4+1] = v.y;
        myvals[it*4+2] = v.z; myvals[it*4+3] = v.w;
    }
    int cnt = 0;
    #pragma unroll
    for (int j = 0; j < 32; ++j) {
        int idx  = (j >> 2) * 256 + lane * 4 + (j & 3);
        bool hit = (myvals[j] == c);
        unsigned long long m = __ballot(hit);
        if (hit) {
            int pos = cnt + (int)__popcll(m & ((1ull << lane) - 1ull));
            if (pos < MAXTOK) toktmp[pos] = idx;
        }
        cnt += (int)__popcll(m);
    }
    const int cnt1 = cnt < 16 ? cnt : 16;

    const int p0   = wid;
    const int p1   = 8 + wid;             // valid only for wid<5 (p1<=12)
    const int npan = (wid < 5) ? 2 : 1;

    int tkS[4]; bool msk[4]; float bias0 = 0.f, bias1 = 0.f;
    if (cnt) {
        int mytokA = toktmp[n < cnt1 ? n : cnt1 - 1];
        #pragma unroll
        for (int i = 0; i < 4; ++i) {
            tkS[i] = __shfl(mytokA, q * 4 + i);
            msk[i] = (q * 4 + i) < cnt1;
        }
        { int rr = p0 * 16 + n; if (rr > CHUNK - 1) rr = CHUNK - 1;
          bias0 = bw[c * CHUNK + rr]; }
        if (npan == 2) {
            int rr = p1 * 16 + n; if (rr > CHUNK - 1) rr = CHUNK - 1;
            bias1 = bw[c * CHUNK + rr];
        }
        // ---- stage A once: split-bf16 fragments, XOR-swizzled slots ----
        // job = (tok, kstep, qslice); 1024 jobs over 512 threads
        #pragma unroll
        for (int rep = 0; rep < 2; ++rep) {
            int job = tid * 2 + rep;
            int tok = job >> 6, s = (job >> 2) & 15, qq = job & 3;
            int ti  = toktmp[tok < cnt1 ? tok : cnt1 - 1];
            const float* xp = x + (size_t)ti * NHID + s * 32 + qq * 8;
            float4 a0 = *(const float4*)xp, a1 = *(const float4*)(xp + 4);
            bf16x8 hh, ll; cvt8(a0, a1, hh, ll);
            char* ab = (char*)Afrag + tok * 2048 + s * 128;
            *(bf16x8*)(ab + (((qq * 2    ) ^ (tok & 7)) << 4)) = hh;
            *(bf16x8*)(ab + (((qq * 2 + 1) ^ (tok & 7)) << 4)) = ll;
        }
    }
    __syncthreads();   // A staged; everything pre-loop retired (full drain here)

    // ================= word streams: 8 independent pipelines ================
    if (cnt) {
        const float* wbase = Ww + (size_t)c * CHUNK * NHID;
        float* rb0 = (wid < 5) ? &ringA[wid][0][0] : &ringB[wid - 5][0];
        float* rb1 = (wid < 5) ? &ringA[wid][1][0] : rb0;
        const int depth = (wid < 5) ? 2 : 1;
        const int nQ    = npan * 4;

        issue_quarter(wbase, p0, 0, rb0, lane);
        if (depth == 2) issue_quarter(wbase, p0, 1, rb1, lane);

        f32x4 acc = {0.f, 0.f, 0.f, 0.f};
        for (int iq = 0; iq < nQ; ++iq) {
            // counted pacing: never drain mid-stream (loads span iterations)
            if (depth == 2 && iq != nQ - 1)
                asm volatile("s_waitcnt vmcnt(8)" ::: "memory");
            else
                asm volatile("s_waitcnt vmcnt(0)" ::: "memory");

            const int kq = iq & 3;
            const float* qb = (depth == 2 && (iq & 1)) ? rb1 : rb0;
            if (kq == 0) { acc[0]=0.f; acc[1]=0.f; acc[2]=0.f; acc[3]=0.f; }

            #pragma unroll
            for (int t4 = 0; t4 < 4; ++t4) {
                const int s = kq * 4 + t4;
                const char* ab = (const char*)Afrag + n * 2048 + s * 128;
                bf16x8 ah = *(const bf16x8*)(ab + (((q*2    ) ^ (n&7)) << 4));
                bf16x8 al = *(const bf16x8*)(ab + (((q*2 + 1) ^ (n&7)) << 4));
                const float* bp = qb + n * 128 + t4 * 32;
                float4 b0 = *(const float4*)(bp + (((q*2    ) ^ (n&7)) << 2));
                float4 b1 = *(const float4*)(bp + (((q*2 + 1) ^ (n&7)) << 2));
                bf16x8 bh, bl; cvt8(b0, b1, bh, bl);
                acc = MFMA(ah, bh, acc);
                acc = MFMA(al, bh, acc);
                acc = MFMA(ah, bl, acc);
            }

            if (kq == 3) {
                const int   P = (iq >= 4) ? p1 : p0;
                const int   r = P * 16 + n;
                const float biasP = (iq >= 4) ? bias1 : bias0;
                if (r < CHUNK) {
                    #pragma unroll
                    for (int i = 0; i < 4; ++i)
                        if (msk[i])
                            out[(size_t)tkS[i] * NOUT + NCLS + r] = acc[i] + biasP;
                }
            }

            const int nx = iq + depth;
            if (nx < nQ)
                issue_quarter(wbase, (nx >= 4) ? p1 : p0, nx & 3,
                              (depth == 2 && (nx & 1)) ? rb1 : rb0, lane);
        }
    }

    // ================= p_class tail: 8-way split of one unit ================
    class_unit(c, wid, lane, n, q, x, Wc, bc, out);
    if (c < 6) class_unit(NCLS + c, wid, lane, n, q, x, Wc, bc, out);

    // ============ rare overflow (cnt>16): scalar-FMA residual tail ==========
    if (cnt > 16) {
        const int cw = cnt < MAXTOK ? cnt : MAXTOK;
        const int ov = cw - 16;
        for (int j = tid; j < ov * CHUNK; j += NTHR) {
            const int g  = j / CHUNK;
            const int rr = j - g * CHUNK;
            const int ti = toktmp[16 + g];
            const float4* wr = (const float4*)(Ww + ((size_t)c * CHUNK + rr) * NHID);
            const float4* xr = (const float4*)(x + (size_t)ti * NHID);
            float s0 = 0.f, s1 = 0.f, s2 = 0.f, s3 = 0.f;
            #pragma unroll 4
            for (int k = 0; k < 128; ++k) {
                float4 a = wr[k], b = xr[k];
                s0 += a.x * b.x; s1 += a.y * b.y;
                s2 += a.z * b.z; s3 += a.w * b.w;
            }
            out[(size_t)ti * NOUT + NCLS + rr] =
                (s0 + s1) + (s2 + s3) + bw[c * CHUNK + rr];
        }
    }
}

extern "C" void kernel_launch(void* const* d_in, const int* in_sizes, int n_in,
                              void* d_out, int out_size, void* d_ws, size_t ws_size,
                              hipStream_t stream) {
    const float* x   = (const float*)d_in[0];
    const float* Wc  = (const float*)d_in[1];
    const float* bc  = (const float*)d_in[2];
    const float* Ww  = (const float*)d_in[3];
    const float* bw  = (const float*)d_in[4];
    const int*   cls = (const int*)d_in[5];
    float* out = (float*)d_out;
    hipLaunchKernelGGL(cbd_fused, dim3(NBLK), dim3(NTHR), 0, stream,
                       x, Wc, bc, Ww, bw, cls, out);
}